// Round 6
// baseline (408.711 us; speedup 1.0000x reference)
//
#include <hip/hip_runtime.h>
#include <math.h>

typedef unsigned short u16;
typedef unsigned int u32;
typedef _Float16 f16x8 __attribute__((ext_vector_type(8)));
typedef float f32x4 __attribute__((ext_vector_type(4)));
typedef u16 u16x4 __attribute__((ext_vector_type(4)));

__device__ __forceinline__ u16 f2h(float x) {
  _Float16 h = (_Float16)x;
  return __builtin_bit_cast(u16, h);
}
__device__ __forceinline__ float h2f(u16 u) {
  return (float)__builtin_bit_cast(_Float16, u);
}

__device__ __forceinline__ void gload16(const void* g, void* l) {
  __builtin_amdgcn_global_load_lds(
      (const __attribute__((address_space(1))) void*)g,
      (__attribute__((address_space(3))) void*)l, 16, 0, 0);
}

// ---------------------------------------------------------------------------
// 8-phase NT GEMM, fp16 in / f32 acc (mfma_f32_16x16x32_f16).
// A [M,lda] rm, B [N,ldb] rm, C[m][n] = sum_k A[m][k]*B[n][k].
// Tile 256 x (64*JF), BK=64, 8 waves (2Mx4N).  LDS 2 x (32KB A + JF*8KB B),
// XOR slot swizzle, pre-swizzled global source, linear gload_lds dest.
// R6 change: A-fragment ds_reads for phase p+1 issue DURING phase p's MFMA
// cluster (double-buffered af regs) so the LDS pipe overlaps the MFMA pipe.
// Race-free: buf[cur].A is never written during tile s (stages write
// buf[cur^1].A and buf[cur].B(s+2)); B is read once at tile start (analyzed
// race-free in R3).  Tile-boundary phase 0 stays serial (vmcnt drain).
// Staging map per tile s (cur=s&1):
//   p0: stageA.h0(s+1)->buf[cur^1]; p1: stageA.h1(s+1) + stageB.h0(s+2)->
//   buf[cur]; p2 (JF4): stageB.h1(s+2); last: counted vmcnt(JF) -> drains
//   exactly tile s+1, B(s+2) stays in flight.
// EPI: 1=scores f32, 2=+resid f32, 3=+bias+gelu->fp16, 4=+bias+resid->f32,
//      5=plain fp16
// ---------------------------------------------------------------------------
template <int JF, int NPH, int EPI, bool SWZ>
__global__ __launch_bounds__(512, 2) void gemm8(
    const u16* __restrict__ A, const u16* __restrict__ B, int M, int N, int K,
    int lda, int ldb, long zsA, long zsB, long zsC, float* __restrict__ outF,
    u16* __restrict__ outU, const float* __restrict__ aux0,
    const float* __restrict__ aux1) {
  constexpr int BUF = 32768 + JF * 8192;  // bytes per double-buffer half
  constexpr int IPP = 8 / NPH;            // i-frags per phase
  extern __shared__ __align__(16) char smem[];

  const int tid = threadIdx.x;
  const int lane = tid & 63;
  const int wave = tid >> 6;
  const int z = blockIdx.z;

  int bx = blockIdx.x, by = blockIdx.y;
  if constexpr (SWZ) {
    const int gx = gridDim.x;
    const int nwg = gx * gridDim.y;
    const int id = by * gx + bx;
    const int q = nwg >> 3;  // nwg % 8 == 0 for all our grids
    const int id2 = (id & 7) * q + (id >> 3);
    bx = id2 % gx;
    by = id2 / gx;
  }
  const long row0 = (long)by * 256;
  const long col0 = (long)bx * (64 * JF);

  const u16* __restrict__ Ab = A + (long)z * zsA;
  const u16* __restrict__ Bb = B + (long)z * zsB;

  // staging lane geometry (pre-swizzled global slot, linear LDS dest)
  const int srow = lane >> 3;
  const int gslot = (lane & 7) ^ srow;
  // fragment lane geometry
  const int fr = lane & 15;
  const int kgrp = lane >> 4;
  const int wm = (wave >> 2) << 7;        // 0 or 128
  const int wn = (wave & 3) * (16 * JF);

  const int nk = K >> 6;

  // hoisted LDS read bases (kk=1 base = kk=0 base ^ 64, carry-free)
  const int slot0 = kgrp ^ (fr & 7);
  const int offA0 = (wm + fr) * 128 + slot0 * 16;
  const int offA1 = offA0 ^ 64;
  const int offB0 = 32768 + (wn + fr) * 128 + slot0 * 16;
  const int offB1 = offB0 ^ 64;

  // hoisted staging bases
  const u16* const gA0 = Ab + (row0 + wave * 16 + srow) * (long)lda + gslot * 8;
  const u16* const gA1 = gA0 + 128 * (long)lda;
  const u16* const gB0 = Bb + (col0 + wave * 16 + srow) * (long)ldb + gslot * 8;
  const u16* const gB1 = gB0 + 128 * (long)ldb;
  char* const dA = smem + wave * 2048 + lane * 16;
  char* const dB = dA + 32768;

  f32x4 acc[8][JF] = {};
  f16x8 bfrag[2][JF];

  auto stageA = [&](int buf, int kt, int h) {
    const long ko = (long)kt * 64;
    const u16* g = (h ? gA1 : gA0) + ko;
    char* d = dA + buf * BUF + (h ? 16384 : 0);
    gload16(g, d);
    gload16(g + 8 * (long)lda, d + 1024);
  };
  auto stageB = [&](int buf, int kt, int h) {
    const long ko = (long)kt * 64;
    const u16* g = (h ? gB1 : gB0) + ko;
    char* d = dB + buf * BUF + (h ? 16384 : 0);
    gload16(g, d);
    gload16(g + 8 * (long)ldb, d + 1024);
  };

  // prologue: tile0 (A+B) -> buf0; tile1's B -> buf1.  Drain tile0 only.
  stageA(0, 0, 0);
  stageA(0, 0, 1);
  stageB(0, 0, 0);
  if constexpr (JF == 4) stageB(0, 0, 1);
  stageB(1, 1, 0);
  if constexpr (JF == 4) stageB(1, 1, 1);
  if constexpr (JF == 4)
    asm volatile("s_waitcnt vmcnt(4)");
  else
    asm volatile("s_waitcnt vmcnt(2)");
  __builtin_amdgcn_s_barrier();

  for (int s = 0; s < nk; ++s) {
    const int cur = s & 1;
    const bool stA = (s + 1 < nk);
    const bool stB = (s + 2 < nk);
    const char* sb = smem + cur * BUF;
    const char* pA0 = sb + offA0;
    const char* pA1 = sb + offA1;
    const char* pB0 = sb + offB0;
    const char* pB1 = sb + offB1;

    // tile-start reads: phase-0 A frags + ALL B frags (buf stable post-drain)
    f16x8 afc[IPP][2], afn[IPP][2];
#pragma unroll
    for (int ii = 0; ii < IPP; ++ii) {
      afc[ii][0] = *(const f16x8*)(pA0 + ii * 2048);
      afc[ii][1] = *(const f16x8*)(pA1 + ii * 2048);
    }
#pragma unroll
    for (int j = 0; j < JF; ++j) {
      bfrag[0][j] = *(const f16x8*)(pB0 + j * 2048);
      bfrag[1][j] = *(const f16x8*)(pB1 + j * 2048);
    }

#pragma unroll
    for (int p = 0; p < NPH; ++p) {
      // staging (pre-barrier)
      if (p == 0 && stA) stageA(cur ^ 1, s + 1, 0);
      if (p == 1) {
        if (stA) stageA(cur ^ 1, s + 1, 1);
        if (stB) stageB(cur, s + 2, 0);
      }
      if constexpr (NPH == 4) {
        if (p == 2 && stB) stageB(cur, s + 2, 1);
      }
      __builtin_amdgcn_s_barrier();
      asm volatile("s_waitcnt lgkmcnt(0)");
      // prefetch NEXT phase's A frags; LDS pipe runs under the MFMA cluster
      if (p + 1 < NPH) {
#pragma unroll
        for (int ii = 0; ii < IPP; ++ii) {
          afn[ii][0] = *(const f16x8*)(pA0 + ((p + 1) * IPP + ii) * 2048);
          afn[ii][1] = *(const f16x8*)(pA1 + ((p + 1) * IPP + ii) * 2048);
        }
      }
      __builtin_amdgcn_s_setprio(1);
#pragma unroll
      for (int kk = 0; kk < 2; ++kk)
#pragma unroll
        for (int ii = 0; ii < IPP; ++ii)
#pragma unroll
          for (int j = 0; j < JF; ++j)
            acc[p * IPP + ii][j] = __builtin_amdgcn_mfma_f32_16x16x32_f16(
                afc[ii][kk], bfrag[kk][j], acc[p * IPP + ii][j], 0, 0, 0);
      __builtin_amdgcn_s_setprio(0);
      if (p == NPH - 1) {
        if (stB) {
          if constexpr (JF == 4)
            asm volatile("s_waitcnt vmcnt(4)");
          else
            asm volatile("s_waitcnt vmcnt(2)");
        } else {
          asm volatile("s_waitcnt vmcnt(0)");
        }
      }
      __builtin_amdgcn_s_barrier();
      // swap (unrolled -> register renaming, no moves)
      if (p + 1 < NPH) {
#pragma unroll
        for (int ii = 0; ii < IPP; ++ii) {
          afc[ii][0] = afn[ii][0];
          afc[ii][1] = afn[ii][1];
        }
      }
    }
  }

  // epilogue: C/D frag layout: col = lane&15 (fr), row = kgrp*4 + r
#pragma unroll
  for (int i = 0; i < 8; ++i) {
#pragma unroll
    for (int j = 0; j < JF; ++j) {
#pragma unroll
      for (int r = 0; r < 4; ++r) {
        const long m = row0 + wm + i * 16 + (kgrp << 2) + r;
        const long n = col0 + wn + j * 16 + fr;
        const float val = acc[i][j][r];
        if constexpr (EPI == 1) {
          outF[(long)z * zsC + m * (long)N + n] = val;
        } else if constexpr (EPI == 2) {
          const long idx = (long)z * zsC + m * (long)N + n;
          outF[idx] = val + aux0[idx];
        } else if constexpr (EPI == 3) {
          const float t = val + aux0[n];
          const float gl = 0.5f * t * (1.0f + erff(t * 0.70710678118654752f));
          outU[m * (long)N + n] = f2h(gl);
        } else if constexpr (EPI == 4) {
          outF[m * (long)N + n] = val + aux0[n] + aux1[m * (long)N + n];
        } else {
          outU[m * (long)N + n] = f2h(val);
        }
      }
    }
  }
}

// ---------------------------------------------------------------------------
// LayerNorm over D=1024, one wave per row, 4 rows/block, fp16 out.
// ---------------------------------------------------------------------------
__global__ __launch_bounds__(256) void ln_k(const float* __restrict__ x,
                                            const float* __restrict__ gw,
                                            const float* __restrict__ bw,
                                            u16* __restrict__ out) {
  const int lane = threadIdx.x & 63;
  const int wv = threadIdx.x >> 6;
  const long row = (long)blockIdx.x * 4 + wv;
  const float* xr = x + row * 1024;
  float4 v[4];
  float s = 0.f, ss = 0.f;
#pragma unroll
  for (int j = 0; j < 4; ++j) {
    v[j] = *(const float4*)(xr + (lane + 64 * j) * 4);
    s += v[j].x + v[j].y + v[j].z + v[j].w;
    ss += v[j].x * v[j].x + v[j].y * v[j].y + v[j].z * v[j].z + v[j].w * v[j].w;
  }
#pragma unroll
  for (int o = 32; o; o >>= 1) {
    s += __shfl_xor(s, o);
    ss += __shfl_xor(ss, o);
  }
  const float mu = s * (1.f / 1024.f);
  const float var = ss * (1.f / 1024.f) - mu * mu;
  const float rs = rsqrtf(var + 1e-5f);
  u16* orow = out + row * 1024;
#pragma unroll
  for (int j = 0; j < 4; ++j) {
    const int n = (lane + 64 * j) * 4;
    const float4 gg = *(const float4*)(gw + n);
    const float4 bb = *(const float4*)(bw + n);
    u16x4 H;
    H[0] = f2h((v[j].x - mu) * rs * gg.x + bb.x);
    H[1] = f2h((v[j].y - mu) * rs * gg.y + bb.y);
    H[2] = f2h((v[j].z - mu) * rs * gg.z + bb.z);
    H[3] = f2h((v[j].w - mu) * rs * gg.w + bb.w);
    *(u16x4*)(orow + n) = H;
  }
}

// ---------------------------------------------------------------------------
// Tiled transpose+convert. in [R,C] -> out [C,R] (per z).
// MODE 0: f32 -> fp16;  MODE 2: fp16 -> fp16.
// ---------------------------------------------------------------------------
template <int MODE>
__global__ __launch_bounds__(256) void transpose_k(const void* __restrict__ in,
                                                   u16* __restrict__ out,
                                                   int R, int C, long zsIn,
                                                   long zsOut) {
  __shared__ float tile[32][33];
  const int z = blockIdx.z;
  const int c0 = blockIdx.x * 32, r0 = blockIdx.y * 32;
#pragma unroll
  for (int i = 0; i < 4; ++i) {
    const int lin = threadIdx.x + 256 * i;
    const int rr = lin >> 5, cc = lin & 31;
    float vv;
    if constexpr (MODE == 2)
      vv = h2f(((const u16*)in + (long)z * zsIn)[(long)(r0 + rr) * C + c0 + cc]);
    else
      vv = ((const float*)in)[(long)(r0 + rr) * C + c0 + cc];
    tile[rr][cc] = vv;
  }
  __syncthreads();
  u16* outz = out + (long)z * zsOut;
#pragma unroll
  for (int i = 0; i < 4; ++i) {
    const int lin = threadIdx.x + 256 * i;
    const int oc = lin >> 5, orr = lin & 31;
    outz[(long)(c0 + oc) * R + (r0 + orr)] = f2h(tile[orr][oc]);
  }
}

// ---------------------------------------------------------------------------
// Row softmax over 2048 cols, f32 in -> fp16 out IN-PLACE (P overwrites the
// first 4 KB of each 16 KB score row; all reads precede first barrier).
// ---------------------------------------------------------------------------
__global__ __launch_bounds__(256) void softmax_k(float* __restrict__ S) {
  const long row = blockIdx.x;
  float* sr = S + row * 2048;
  u16* pr = (u16*)sr;
  const int tid = threadIdx.x;
  const int lane = tid & 63, wv = tid >> 6;
  __shared__ float red[8];
  const float4 v0 = *(const float4*)(sr + tid * 4);
  const float4 v1 = *(const float4*)(sr + 1024 + tid * 4);
  float mx = fmaxf(fmaxf(fmaxf(v0.x, v0.y), fmaxf(v0.z, v0.w)),
                   fmaxf(fmaxf(v1.x, v1.y), fmaxf(v1.z, v1.w)));
#pragma unroll
  for (int o = 32; o; o >>= 1) mx = fmaxf(mx, __shfl_xor(mx, o));
  if (lane == 0) red[wv] = mx;
  __syncthreads();
  mx = fmaxf(fmaxf(red[0], red[1]), fmaxf(red[2], red[3]));
  float e[8];
  e[0] = expf(v0.x - mx); e[1] = expf(v0.y - mx);
  e[2] = expf(v0.z - mx); e[3] = expf(v0.w - mx);
  e[4] = expf(v1.x - mx); e[5] = expf(v1.y - mx);
  e[6] = expf(v1.z - mx); e[7] = expf(v1.w - mx);
  float sm = e[0] + e[1] + e[2] + e[3] + e[4] + e[5] + e[6] + e[7];
#pragma unroll
  for (int o = 32; o; o >>= 1) sm += __shfl_xor(sm, o);
  if (lane == 0) red[4 + wv] = sm;
  __syncthreads();
  sm = red[4] + red[5] + red[6] + red[7];
  const float inv = 1.f / sm;
  u16x4 a, b;
  a[0] = f2h(e[0] * inv); a[1] = f2h(e[1] * inv);
  a[2] = f2h(e[2] * inv); a[3] = f2h(e[3] * inv);
  b[0] = f2h(e[4] * inv); b[1] = f2h(e[5] * inv);
  b[2] = f2h(e[6] * inv); b[3] = f2h(e[7] * inv);
  *(u16x4*)(pr + tid * 4) = a;
  *(u16x4*)(pr + 1024 + tid * 4) = b;
}

// ---------------------------------------------------------------------------
extern "C" void kernel_launch(void* const* d_in, const int* in_sizes, int n_in,
                              void* d_out, int out_size, void* d_ws,
                              size_t ws_size, hipStream_t stream) {
  const float* x     = (const float*)d_in[0];  // [4,2048,1024]
  const float* w_qkv = (const float*)d_in[1];  // [1024,3072]
  const float* fc1_w = (const float*)d_in[2];  // [1024,4096]
  const float* fc1_b = (const float*)d_in[3];  // [4096]
  const float* fc2_w = (const float*)d_in[4];  // [4096,1024]
  const float* fc2_b = (const float*)d_in[5];  // [1024]
  const float* ln1_g = (const float*)d_in[6];
  const float* ln1_b = (const float*)d_in[7];
  const float* ln2_g = (const float*)d_in[8];
  const float* ln2_b = (const float*)d_in[9];
  float* out = (float*)d_out;

  // workspace (peak 160 MB, phase-aliased; all fp16 unless noted)
  char* ws = (char*)d_ws;
  const long MB = 1024L * 1024L;
  u16*   h    = (u16*)(ws + 0);          // 16MB [8192,1024]
  u16*   wqkT = (u16*)(ws + 16 * MB);    //  6MB [3072,1024]
  float* sc   = (float*)(ws + 0);        // 64MB f32 scores (h,wqkT dead)
  u16*   qk   = (u16*)(ws + 64 * MB);    // 32MB [8192,2048] (q|k)
  u16*   vbuf = (u16*)(ws + 96 * MB);    // 16MB [8192,1024]
  u16*   vT   = (u16*)(ws + 112 * MB);   // 16MB [4][1024][2048]
  u16*   w1T  = (u16*)(ws + 144 * MB);   //  8MB [4096,1024]
  u16*   w2T  = (u16*)(ws + 152 * MB);   //  8MB [1024,4096]
  float* r2   = (float*)(ws + 64 * MB);  // 32MB f32 (qk dead after GEMM2)
  u16*   h2   = (u16*)(ws + 96 * MB);    // 16MB (vbuf dead after vT)
  u16*   g    = (u16*)(ws + 0);          // 64MB [8192,4096] (sc/P dead)

  dim3 blk(256);
  dim3 blk8(512);
  const int LDS4 = 131072;  // JF=4: 2 x (32KB A + 32KB B)
  const int LDS2 = 98304;   // JF=2: 2 x (32KB A + 16KB B)
  (void)hipFuncSetAttribute((const void*)gemm8<4, 4, 5, true>,
                            hipFuncAttributeMaxDynamicSharedMemorySize, LDS4);
  (void)hipFuncSetAttribute((const void*)gemm8<2, 2, 5, true>,
                            hipFuncAttributeMaxDynamicSharedMemorySize, LDS2);
  (void)hipFuncSetAttribute((const void*)gemm8<4, 4, 1, true>,
                            hipFuncAttributeMaxDynamicSharedMemorySize, LDS4);
  (void)hipFuncSetAttribute((const void*)gemm8<2, 2, 2, true>,
                            hipFuncAttributeMaxDynamicSharedMemorySize, LDS2);
  (void)hipFuncSetAttribute((const void*)gemm8<4, 4, 3, true>,
                            hipFuncAttributeMaxDynamicSharedMemorySize, LDS4);
  (void)hipFuncSetAttribute((const void*)gemm8<2, 2, 4, true>,
                            hipFuncAttributeMaxDynamicSharedMemorySize, LDS2);

  // 1) LN1 -> h fp16
  ln_k<<<2048, blk, 0, stream>>>(x, ln1_g, ln1_b, h);
  // 2) w_qkv [1024,3072] -> wqkT [3072,1024] fp16
  transpose_k<0><<<dim3(3072 / 32, 1024 / 32, 1), blk, 0, stream>>>(
      w_qkv, wqkT, 1024, 3072, 0, 0);
  // 3) qk-GEMM: qk = h @ wqk^T.  grid 256 exact, JF4.
  gemm8<4, 4, 5, true><<<dim3(8, 32, 1), blk8, LDS4, stream>>>(
      h, wqkT, 8192, 2048, 1024, 1024, 1024, 0, 0, 0, nullptr, qk, nullptr,
      nullptr);
  // 4) v-GEMM: vbuf = h @ wv^T.  grid 256 exact, JF2.
  gemm8<2, 2, 5, true><<<dim3(8, 32, 1), blk8, LDS2, stream>>>(
      h, wqkT + 2048L * 1024, 8192, 1024, 1024, 1024, 1024, 0, 0, 0, nullptr,
      vbuf, nullptr, nullptr);
  // 5) v -> vT per batch
  transpose_k<2><<<dim3(1024 / 32, 2048 / 32, 4), blk, 0, stream>>>(
      vbuf, vT, 2048, 1024, 2048L * 1024, 1024L * 2048);
  // 6) GEMM2: scores[z] = q[z] @ k[z]^T (fp16, K=1024).  grid 64/z.
  gemm8<4, 4, 1, true><<<dim3(8, 8, 4), blk8, LDS4, stream>>>(
      qk, qk + 1024, 2048, 2048, 1024, 2048, 2048, 2048L * 2048, 2048L * 2048,
      2048L * 2048, sc, nullptr, nullptr, nullptr);
  // 7) softmax in-place: P (fp16, lda=4096 u16) overwrites score rows
  softmax_k<<<8192, blk, 0, stream>>>(sc);
  // 8) GEMM3: attn = P @ vT + resid -> r2.  grid 64/z, JF2.
  gemm8<2, 2, 2, true><<<dim3(8, 8, 4), blk8, LDS2, stream>>>(
      (const u16*)sc, vT, 2048, 1024, 2048, 4096, 2048, 2048L * 4096,
      1024L * 2048, 2048L * 1024, r2, nullptr, x, nullptr);
  // 9) LN2 -> h2 fp16
  ln_k<<<2048, blk, 0, stream>>>(r2, ln2_g, ln2_b, h2);
  // 10) fc1_w -> w1T, fc2_w -> w2T
  transpose_k<0><<<dim3(4096 / 32, 1024 / 32, 1), blk, 0, stream>>>(
      fc1_w, w1T, 1024, 4096, 0, 0);
  transpose_k<0><<<dim3(1024 / 32, 4096 / 32, 1), blk, 0, stream>>>(
      fc2_w, w2T, 4096, 1024, 0, 0);
  // 11) GEMM4: g = gelu(h2 @ fc1_w + b1) fp16.  grid 512 = 2 exact waves.
  gemm8<4, 4, 3, true><<<dim3(16, 32, 1), blk8, LDS4, stream>>>(
      h2, w1T, 8192, 4096, 1024, 1024, 1024, 0, 0, 0, nullptr, g, fc1_b,
      nullptr);
  // 12) GEMM5: out = g @ fc2_w + b2 + r2.  grid 256 exact, JF2.
  gemm8<2, 2, 4, true><<<dim3(8, 32, 1), blk8, LDS2, stream>>>(
      g, w2T, 8192, 1024, 4096, 4096, 4096, 0, 0, 0, out, nullptr, fc2_b, r2);
}

// Round 7
// 377.266 us; speedup vs baseline: 1.0834x; 1.0834x over previous
//
#include <hip/hip_runtime.h>
#include <math.h>

typedef unsigned short u16;
typedef unsigned int u32;
typedef _Float16 f16x8 __attribute__((ext_vector_type(8)));
typedef float f32x4 __attribute__((ext_vector_type(4)));
typedef u16 u16x4 __attribute__((ext_vector_type(4)));

__device__ __forceinline__ u16 f2h(float x) {
  _Float16 h = (_Float16)x;
  return __builtin_bit_cast(u16, h);
}
__device__ __forceinline__ float h2f(u16 u) {
  return (float)__builtin_bit_cast(_Float16, u);
}

__device__ __forceinline__ void gload16(const void* g, void* l) {
  __builtin_amdgcn_global_load_lds(
      (const __attribute__((address_space(1))) void*)g,
      (__attribute__((address_space(3))) void*)l, 16, 0, 0);
}

// ---------------------------------------------------------------------------
// m97-style NT GEMM (R1 engine, fp16): A [M,lda] rm, B [N,ldb] rm,
// C[m][n] = sum_k A[m][k]*B[n][k].  128x128 tile, BK=64, 4 waves (2x2), each
// wave 64x64 = 4x4 frags of 16x16, mfma_f32_16x16x32_f16.
// LDS 32KB single-buffered (2-3 blocks/CU -> m114 cross-block overlap hides
// the barrier drain; R1 measured 39.4% MfmaUtil / 868-875 TF with this exact
// structure).  XOR slot swizzle (slot16 ^= row&7), pre-swizzled global
// source, linear global_load_lds dest (zero bank conflicts, R1-measured).
// EPI: 0=qkv-split fp16 (n<2048 -> qk, else v), 1=scores f32, 2=+resid f32,
//      3=+bias+gelu->fp16, 4=+bias+resid->f32 (final out)
// ---------------------------------------------------------------------------
template <int EPI, bool SWZ>
__global__ __launch_bounds__(256, 2) void gemm_nt(
    const u16* __restrict__ A, const u16* __restrict__ B, int M, int N, int K,
    int lda, int ldb, long zsA, long zsB, long zsC, float* __restrict__ outF,
    u16* __restrict__ outU, u16* __restrict__ outU2,
    const float* __restrict__ aux0, const float* __restrict__ aux1) {
  __shared__ char smem[2 * 128 * 64 * 2];  // 32 KiB: sA | sB
  char* sA = smem;
  char* sB = smem + 16384;

  const int tid = threadIdx.x;
  const int lane = tid & 63;
  const int wave = tid >> 6;
  const int z = blockIdx.z;

  int bx = blockIdx.x, by = blockIdx.y;
  if constexpr (SWZ) {
    const int gx = gridDim.x;
    const int nwg = gx * gridDim.y;  // all our per-z grids are %8 == 0
    const int id = by * gx + bx;
    const int q = nwg >> 3;
    const int id2 = (id & 7) * q + (id >> 3);
    bx = id2 % gx;
    by = id2 / gx;
  }
  const long row0 = (long)by * 128;
  const long col0 = (long)bx * 128;

  const u16* __restrict__ Ab = A + (long)z * zsA;
  const u16* __restrict__ Bb = B + (long)z * zsB;

  // staging geometry: 16 chunks of 8 rows; lane covers (srow, slot) with
  // pre-swizzled global k-slot so the linear LDS dest ends up XOR-swizzled.
  const int srow = lane >> 3;
  const int sslot = (lane & 7) ^ srow;

  const int wm = (wave >> 1) << 6;  // wave row offset in tile
  const int wn = (wave & 1) << 6;   // wave col offset in tile
  const int fr = lane & 15;
  const int kgrp = lane >> 4;

  f32x4 acc[4][4] = {};
  const int nk = K >> 6;

  auto stage = [&](int kt) {
#pragma unroll
    for (int c = 0; c < 4; ++c) {
      const int chunk = wave * 4 + c;  // 0..15, 8 rows each
      const int r = chunk * 8 + srow;
      gload16(Ab + (row0 + r) * (long)lda + kt * 64 + sslot * 8,
              sA + chunk * 1024);
      gload16(Bb + (col0 + r) * (long)ldb + kt * 64 + sslot * 8,
              sB + chunk * 1024);
    }
  };

  stage(0);
  for (int kt = 0; kt < nk; ++kt) {
    __syncthreads();  // drains vmcnt(0) before s_barrier -> staged LDS ready
#pragma unroll
    for (int kk = 0; kk < 2; ++kk) {
      f16x8 af[4], bg[4];
#pragma unroll
      for (int i = 0; i < 4; ++i) {
        const int r = wm + i * 16 + fr;
        const int slot = ((kk << 2) | kgrp) ^ (r & 7);
        af[i] = *(const f16x8*)(sA + r * 128 + slot * 16);
      }
#pragma unroll
      for (int j = 0; j < 4; ++j) {
        const int r = wn + j * 16 + fr;
        const int slot = ((kk << 2) | kgrp) ^ (r & 7);
        bg[j] = *(const f16x8*)(sB + r * 128 + slot * 16);
      }
#pragma unroll
      for (int i = 0; i < 4; ++i)
#pragma unroll
        for (int j = 0; j < 4; ++j)
          acc[i][j] = __builtin_amdgcn_mfma_f32_16x16x32_f16(af[i], bg[j],
                                                             acc[i][j], 0, 0, 0);
    }
    __syncthreads();  // all waves done reading before restage
    if (kt + 1 < nk) stage(kt + 1);
  }

  // epilogue: C/D frag layout (verified): col = lane&15, row = kgrp*4 + r
#pragma unroll
  for (int i = 0; i < 4; ++i) {
#pragma unroll
    for (int j = 0; j < 4; ++j) {
#pragma unroll
      for (int r = 0; r < 4; ++r) {
        const long m = row0 + wm + i * 16 + (kgrp << 2) + r;
        const long n = col0 + wn + j * 16 + fr;
        const float val = acc[i][j][r];
        if constexpr (EPI == 0) {
          if (n < 2048)
            outU[m * 2048 + n] = f2h(val);
          else
            outU2[m * 1024 + (n - 2048)] = f2h(val);
        } else if constexpr (EPI == 1) {
          outF[(long)z * zsC + m * (long)N + n] = val;
        } else if constexpr (EPI == 2) {
          const long idx = (long)z * zsC + m * (long)N + n;
          outF[idx] = val + aux0[idx];
        } else if constexpr (EPI == 3) {
          const float t = val + aux0[n];
          const float gl = 0.5f * t * (1.0f + erff(t * 0.70710678118654752f));
          outU[m * (long)N + n] = f2h(gl);
        } else {
          outF[m * (long)N + n] = val + aux0[n] + aux1[m * (long)N + n];
        }
      }
    }
  }
}

// ---------------------------------------------------------------------------
// LayerNorm over D=1024, one wave per row, 4 rows/block, fp16 out.
// ---------------------------------------------------------------------------
__global__ __launch_bounds__(256) void ln_k(const float* __restrict__ x,
                                            const float* __restrict__ gw,
                                            const float* __restrict__ bw,
                                            u16* __restrict__ out) {
  const int lane = threadIdx.x & 63;
  const int wv = threadIdx.x >> 6;
  const long row = (long)blockIdx.x * 4 + wv;
  const float* xr = x + row * 1024;
  float4 v[4];
  float s = 0.f, ss = 0.f;
#pragma unroll
  for (int j = 0; j < 4; ++j) {
    v[j] = *(const float4*)(xr + (lane + 64 * j) * 4);
    s += v[j].x + v[j].y + v[j].z + v[j].w;
    ss += v[j].x * v[j].x + v[j].y * v[j].y + v[j].z * v[j].z + v[j].w * v[j].w;
  }
#pragma unroll
  for (int o = 32; o; o >>= 1) {
    s += __shfl_xor(s, o);
    ss += __shfl_xor(ss, o);
  }
  const float mu = s * (1.f / 1024.f);
  const float var = ss * (1.f / 1024.f) - mu * mu;
  const float rs = rsqrtf(var + 1e-5f);
  u16* orow = out + row * 1024;
#pragma unroll
  for (int j = 0; j < 4; ++j) {
    const int n = (lane + 64 * j) * 4;
    const float4 gg = *(const float4*)(gw + n);
    const float4 bb = *(const float4*)(bw + n);
    u16x4 H;
    H[0] = f2h((v[j].x - mu) * rs * gg.x + bb.x);
    H[1] = f2h((v[j].y - mu) * rs * gg.y + bb.y);
    H[2] = f2h((v[j].z - mu) * rs * gg.z + bb.z);
    H[3] = f2h((v[j].w - mu) * rs * gg.w + bb.w);
    *(u16x4*)(orow + n) = H;
  }
}

// ---------------------------------------------------------------------------
// Tiled transpose+convert. in [R,C] -> out [C,R] (per z).
// MODE 0: f32 -> fp16;  MODE 2: fp16 -> fp16.
// ---------------------------------------------------------------------------
template <int MODE>
__global__ __launch_bounds__(256) void transpose_k(const void* __restrict__ in,
                                                   u16* __restrict__ out,
                                                   int R, int C, long zsIn,
                                                   long zsOut) {
  __shared__ float tile[32][33];
  const int z = blockIdx.z;
  const int c0 = blockIdx.x * 32, r0 = blockIdx.y * 32;
#pragma unroll
  for (int i = 0; i < 4; ++i) {
    const int lin = threadIdx.x + 256 * i;
    const int rr = lin >> 5, cc = lin & 31;
    float vv;
    if constexpr (MODE == 2)
      vv = h2f(((const u16*)in + (long)z * zsIn)[(long)(r0 + rr) * C + c0 + cc]);
    else
      vv = ((const float*)in)[(long)(r0 + rr) * C + c0 + cc];
    tile[rr][cc] = vv;
  }
  __syncthreads();
  u16* outz = out + (long)z * zsOut;
#pragma unroll
  for (int i = 0; i < 4; ++i) {
    const int lin = threadIdx.x + 256 * i;
    const int oc = lin >> 5, orr = lin & 31;
    outz[(long)(c0 + oc) * R + (r0 + orr)] = f2h(tile[orr][oc]);
  }
}

// ---------------------------------------------------------------------------
// Row softmax over 2048 cols, f32 in -> fp16 out IN-PLACE (P overwrites the
// first 4 KB of each 16 KB score row; all reads precede first barrier).
// ---------------------------------------------------------------------------
__global__ __launch_bounds__(256) void softmax_k(float* __restrict__ S) {
  const long row = blockIdx.x;
  float* sr = S + row * 2048;
  u16* pr = (u16*)sr;
  const int tid = threadIdx.x;
  const int lane = tid & 63, wv = tid >> 6;
  __shared__ float red[8];
  const float4 v0 = *(const float4*)(sr + tid * 4);
  const float4 v1 = *(const float4*)(sr + 1024 + tid * 4);
  float mx = fmaxf(fmaxf(fmaxf(v0.x, v0.y), fmaxf(v0.z, v0.w)),
                   fmaxf(fmaxf(v1.x, v1.y), fmaxf(v1.z, v1.w)));
#pragma unroll
  for (int o = 32; o; o >>= 1) mx = fmaxf(mx, __shfl_xor(mx, o));
  if (lane == 0) red[wv] = mx;
  __syncthreads();
  mx = fmaxf(fmaxf(red[0], red[1]), fmaxf(red[2], red[3]));
  float e[8];
  e[0] = expf(v0.x - mx); e[1] = expf(v0.y - mx);
  e[2] = expf(v0.z - mx); e[3] = expf(v0.w - mx);
  e[4] = expf(v1.x - mx); e[5] = expf(v1.y - mx);
  e[6] = expf(v1.z - mx); e[7] = expf(v1.w - mx);
  float sm = e[0] + e[1] + e[2] + e[3] + e[4] + e[5] + e[6] + e[7];
#pragma unroll
  for (int o = 32; o; o >>= 1) sm += __shfl_xor(sm, o);
  if (lane == 0) red[4 + wv] = sm;
  __syncthreads();
  sm = red[4] + red[5] + red[6] + red[7];
  const float inv = 1.f / sm;
  u16x4 a, b;
  a[0] = f2h(e[0] * inv); a[1] = f2h(e[1] * inv);
  a[2] = f2h(e[2] * inv); a[3] = f2h(e[3] * inv);
  b[0] = f2h(e[4] * inv); b[1] = f2h(e[5] * inv);
  b[2] = f2h(e[6] * inv); b[3] = f2h(e[7] * inv);
  *(u16x4*)(pr + tid * 4) = a;
  *(u16x4*)(pr + 1024 + tid * 4) = b;
}

// ---------------------------------------------------------------------------
extern "C" void kernel_launch(void* const* d_in, const int* in_sizes, int n_in,
                              void* d_out, int out_size, void* d_ws,
                              size_t ws_size, hipStream_t stream) {
  const float* x     = (const float*)d_in[0];  // [4,2048,1024]
  const float* w_qkv = (const float*)d_in[1];  // [1024,3072]
  const float* fc1_w = (const float*)d_in[2];  // [1024,4096]
  const float* fc1_b = (const float*)d_in[3];  // [4096]
  const float* fc2_w = (const float*)d_in[4];  // [4096,1024]
  const float* fc2_b = (const float*)d_in[5];  // [1024]
  const float* ln1_g = (const float*)d_in[6];
  const float* ln1_b = (const float*)d_in[7];
  const float* ln2_g = (const float*)d_in[8];
  const float* ln2_b = (const float*)d_in[9];
  float* out = (float*)d_out;

  // workspace (peak 160 MB, phase-aliased; all fp16 unless noted)
  char* ws = (char*)d_ws;
  const long MB = 1024L * 1024L;
  u16*   h    = (u16*)(ws + 0);          // 16MB [8192,1024]
  u16*   wqkT = (u16*)(ws + 16 * MB);    //  6MB [3072,1024]
  float* sc   = (float*)(ws + 0);        // 64MB f32 scores (h,wqkT dead)
  u16*   qk   = (u16*)(ws + 64 * MB);    // 32MB [8192,2048] (q|k)
  u16*   vbuf = (u16*)(ws + 96 * MB);    // 16MB [8192,1024]
  u16*   vT   = (u16*)(ws + 112 * MB);   // 16MB [4][1024][2048]
  u16*   w1T  = (u16*)(ws + 144 * MB);   //  8MB [4096,1024]
  u16*   w2T  = (u16*)(ws + 152 * MB);   //  8MB [1024,4096]
  float* r2   = (float*)(ws + 64 * MB);  // 32MB f32 (qk dead after GEMM2)
  u16*   h2   = (u16*)(ws + 96 * MB);    // 16MB (vbuf dead after vT)
  u16*   g    = (u16*)(ws + 0);          // 64MB [8192,4096] (sc/P dead)

  dim3 blk(256);

  // 1) LN1 -> h fp16
  ln_k<<<2048, blk, 0, stream>>>(x, ln1_g, ln1_b, h);
  // 2) w_qkv [1024,3072] -> wqkT [3072,1024] fp16
  transpose_k<0><<<dim3(3072 / 32, 1024 / 32, 1), blk, 0, stream>>>(
      w_qkv, wqkT, 1024, 3072, 0, 0);
  // 3) qkv-GEMM: h @ wqkv^T -> qk (n<2048) + vbuf.  grid 1536 = 6 rounds.
  gemm_nt<0, true><<<dim3(24, 64, 1), blk, 0, stream>>>(
      h, wqkT, 8192, 3072, 1024, 1024, 1024, 0, 0, 0, nullptr, qk, vbuf,
      nullptr, nullptr);
  // 4) v -> vT per batch
  transpose_k<2><<<dim3(1024 / 32, 2048 / 32, 4), blk, 0, stream>>>(
      vbuf, vT, 2048, 1024, 2048L * 1024, 1024L * 2048);
  // 5) GEMM2: scores[z] = q[z] @ k[z]^T (fp16, K=1024).  grid 256/z.
  gemm_nt<1, true><<<dim3(16, 16, 4), blk, 0, stream>>>(
      qk, qk + 1024, 2048, 2048, 1024, 2048, 2048, 2048L * 2048, 2048L * 2048,
      2048L * 2048, sc, nullptr, nullptr, nullptr, nullptr);
  // 6) softmax in-place: P (fp16, lda=4096 u16) overwrites score rows
  softmax_k<<<8192, blk, 0, stream>>>(sc);
  // 7) GEMM3: attn = P @ vT + resid -> r2.  grid 128/z.
  gemm_nt<2, true><<<dim3(8, 16, 4), blk, 0, stream>>>(
      (const u16*)sc, vT, 2048, 1024, 2048, 4096, 2048, 2048L * 4096,
      1024L * 2048, 2048L * 1024, r2, nullptr, nullptr, x, nullptr);
  // 8) LN2 -> h2 fp16
  ln_k<<<2048, blk, 0, stream>>>(r2, ln2_g, ln2_b, h2);
  // 9) fc1_w -> w1T, fc2_w -> w2T
  transpose_k<0><<<dim3(4096 / 32, 1024 / 32, 1), blk, 0, stream>>>(
      fc1_w, w1T, 1024, 4096, 0, 0);
  transpose_k<0><<<dim3(1024 / 32, 4096 / 32, 1), blk, 0, stream>>>(
      fc2_w, w2T, 4096, 1024, 0, 0);
  // 10) GEMM4: g = gelu(h2 @ fc1_w + b1) fp16.  grid 2048 = 8 rounds.
  gemm_nt<3, true><<<dim3(32, 64, 1), blk, 0, stream>>>(
      h2, w1T, 8192, 4096, 1024, 1024, 1024, 0, 0, 0, nullptr, g, nullptr,
      fc1_b, nullptr);
  // 11) GEMM5: out = g @ fc2_w + b2 + r2.  grid 512 = 2 rounds.
  gemm_nt<4, true><<<dim3(8, 64, 1), blk, 0, stream>>>(
      g, w2T, 8192, 1024, 4096, 4096, 4096, 0, 0, 0, out, nullptr, nullptr,
      fc2_b, r2);
}

// Round 8
// 375.149 us; speedup vs baseline: 1.0895x; 1.0056x over previous
//
#include <hip/hip_runtime.h>
#include <math.h>

typedef unsigned short u16;
typedef unsigned int u32;
typedef _Float16 f16x8 __attribute__((ext_vector_type(8)));
typedef float f32x4 __attribute__((ext_vector_type(4)));
typedef u16 u16x4 __attribute__((ext_vector_type(4)));

__device__ __forceinline__ u16 f2h(float x) {
  _Float16 h = (_Float16)x;
  return __builtin_bit_cast(u16, h);
}
__device__ __forceinline__ float h2f(u16 u) {
  return (float)__builtin_bit_cast(_Float16, u);
}

// exact-erf GELU via Abramowitz-Stegun 7.1.26 (|err| <= 1.5e-7, far below
// fp16 ulp): erf(s) = 1 - poly(1/(1+0.3275911 s)) * exp(-s^2), s >= 0.
__device__ __forceinline__ float gelu_erf(float x) {
  const float u = x * 0.70710678118654752f;
  const float s = fabsf(u);
  const float t = __frcp_rn(1.0f + 0.3275911f * s);  // rcp; poly tolerates
  float p = 1.061405429f;
  p = p * t - 1.453152027f;
  p = p * t + 1.421413741f;
  p = p * t - 0.284496736f;
  p = p * t + 0.254829592f;
  const float e = __expf(-s * s);  // v_exp_f32 path
  float erf = 1.0f - p * t * e;
  erf = u < 0.0f ? -erf : erf;
  return 0.5f * x * (1.0f + erf);
}

__device__ __forceinline__ void gload16(const void* g, void* l) {
  __builtin_amdgcn_global_load_lds(
      (const __attribute__((address_space(1))) void*)g,
      (__attribute__((address_space(3))) void*)l, 16, 0, 0);
}

// ---------------------------------------------------------------------------
// m97-style NT GEMM (R1 engine, fp16): A [M,lda] rm, B [N,ldb] rm,
// C[m][n] = sum_k A[m][k]*B[n][k].  128x128 tile, BK=64, 4 waves (2x2), each
// wave 64x64 = 4x4 frags of 16x16, mfma_f32_16x16x32_f16.
// LDS 32KB single-buffered (multi-block/CU -> m114 cross-block overlap hides
// the barrier drain; R7 measured 33% MfmaUtil / ~800 TF avg).  XOR slot
// swizzle (slot16 ^= row&7), pre-swizzled global source, linear
// global_load_lds dest (zero bank conflicts, measured).
// EPI: 0=qkv-split fp16 (n<2048 -> qk, else v), 1=scores f32, 2=+resid f32,
//      3=+bias+gelu->fp16 (fast-erf poly), 4=+bias+resid->f32 (final out)
// ---------------------------------------------------------------------------
template <int EPI, bool SWZ>
__global__ __launch_bounds__(256, 4) void gemm_nt(
    const u16* __restrict__ A, const u16* __restrict__ B, int M, int N, int K,
    int lda, int ldb, long zsA, long zsB, long zsC, float* __restrict__ outF,
    u16* __restrict__ outU, u16* __restrict__ outU2,
    const float* __restrict__ aux0, const float* __restrict__ aux1) {
  __shared__ char smem[2 * 128 * 64 * 2];  // 32 KiB: sA | sB
  char* sA = smem;
  char* sB = smem + 16384;

  const int tid = threadIdx.x;
  const int lane = tid & 63;
  const int wave = tid >> 6;
  const int z = blockIdx.z;

  int bx = blockIdx.x, by = blockIdx.y;
  if constexpr (SWZ) {
    const int gx = gridDim.x;
    const int nwg = gx * gridDim.y;  // all our per-z grids are %8 == 0
    const int id = by * gx + bx;
    const int q = nwg >> 3;
    const int id2 = (id & 7) * q + (id >> 3);
    bx = id2 % gx;
    by = id2 / gx;
  }
  const long row0 = (long)by * 128;
  const long col0 = (long)bx * 128;

  const u16* __restrict__ Ab = A + (long)z * zsA;
  const u16* __restrict__ Bb = B + (long)z * zsB;

  // staging geometry: 16 chunks of 8 rows; lane covers (srow, slot) with
  // pre-swizzled global k-slot so the linear LDS dest ends up XOR-swizzled.
  const int srow = lane >> 3;
  const int sslot = (lane & 7) ^ srow;

  const int wm = (wave >> 1) << 6;  // wave row offset in tile
  const int wn = (wave & 1) << 6;   // wave col offset in tile
  const int fr = lane & 15;
  const int kgrp = lane >> 4;

  f32x4 acc[4][4] = {};
  const int nk = K >> 6;

  auto stage = [&](int kt) {
#pragma unroll
    for (int c = 0; c < 4; ++c) {
      const int chunk = wave * 4 + c;  // 0..15, 8 rows each
      const int r = chunk * 8 + srow;
      gload16(Ab + (row0 + r) * (long)lda + kt * 64 + sslot * 8,
              sA + chunk * 1024);
      gload16(Bb + (col0 + r) * (long)ldb + kt * 64 + sslot * 8,
              sB + chunk * 1024);
    }
  };

  stage(0);
  for (int kt = 0; kt < nk; ++kt) {
    __syncthreads();  // drains vmcnt(0) before s_barrier -> staged LDS ready
#pragma unroll
    for (int kk = 0; kk < 2; ++kk) {
      f16x8 af[4], bg[4];
#pragma unroll
      for (int i = 0; i < 4; ++i) {
        const int r = wm + i * 16 + fr;
        const int slot = ((kk << 2) | kgrp) ^ (r & 7);
        af[i] = *(const f16x8*)(sA + r * 128 + slot * 16);
      }
#pragma unroll
      for (int j = 0; j < 4; ++j) {
        const int r = wn + j * 16 + fr;
        const int slot = ((kk << 2) | kgrp) ^ (r & 7);
        bg[j] = *(const f16x8*)(sB + r * 128 + slot * 16);
      }
#pragma unroll
      for (int i = 0; i < 4; ++i)
#pragma unroll
        for (int j = 0; j < 4; ++j)
          acc[i][j] = __builtin_amdgcn_mfma_f32_16x16x32_f16(af[i], bg[j],
                                                             acc[i][j], 0, 0, 0);
    }
    __syncthreads();  // all waves done reading before restage
    if (kt + 1 < nk) stage(kt + 1);
  }

  // epilogue: C/D frag layout (verified): col = lane&15, row = kgrp*4 + r
#pragma unroll
  for (int i = 0; i < 4; ++i) {
#pragma unroll
    for (int j = 0; j < 4; ++j) {
#pragma unroll
      for (int r = 0; r < 4; ++r) {
        const long m = row0 + wm + i * 16 + (kgrp << 2) + r;
        const long n = col0 + wn + j * 16 + fr;
        const float val = acc[i][j][r];
        if constexpr (EPI == 0) {
          if (n < 2048)
            outU[m * 2048 + n] = f2h(val);
          else
            outU2[m * 1024 + (n - 2048)] = f2h(val);
        } else if constexpr (EPI == 1) {
          outF[(long)z * zsC + m * (long)N + n] = val;
        } else if constexpr (EPI == 2) {
          const long idx = (long)z * zsC + m * (long)N + n;
          outF[idx] = val + aux0[idx];
        } else if constexpr (EPI == 3) {
          outU[m * (long)N + n] = f2h(gelu_erf(val + aux0[n]));
        } else {
          outF[m * (long)N + n] = val + aux0[n] + aux1[m * (long)N + n];
        }
      }
    }
  }
}

// ---------------------------------------------------------------------------
// LayerNorm over D=1024, one wave per row, 4 rows/block, fp16 out.
// ---------------------------------------------------------------------------
__global__ __launch_bounds__(256) void ln_k(const float* __restrict__ x,
                                            const float* __restrict__ gw,
                                            const float* __restrict__ bw,
                                            u16* __restrict__ out) {
  const int lane = threadIdx.x & 63;
  const int wv = threadIdx.x >> 6;
  const long row = (long)blockIdx.x * 4 + wv;
  const float* xr = x + row * 1024;
  float4 v[4];
  float s = 0.f, ss = 0.f;
#pragma unroll
  for (int j = 0; j < 4; ++j) {
    v[j] = *(const float4*)(xr + (lane + 64 * j) * 4);
    s += v[j].x + v[j].y + v[j].z + v[j].w;
    ss += v[j].x * v[j].x + v[j].y * v[j].y + v[j].z * v[j].z + v[j].w * v[j].w;
  }
#pragma unroll
  for (int o = 32; o; o >>= 1) {
    s += __shfl_xor(s, o);
    ss += __shfl_xor(ss, o);
  }
  const float mu = s * (1.f / 1024.f);
  const float var = ss * (1.f / 1024.f) - mu * mu;
  const float rs = rsqrtf(var + 1e-5f);
  u16* orow = out + row * 1024;
#pragma unroll
  for (int j = 0; j < 4; ++j) {
    const int n = (lane + 64 * j) * 4;
    const float4 gg = *(const float4*)(gw + n);
    const float4 bb = *(const float4*)(bw + n);
    u16x4 H;
    H[0] = f2h((v[j].x - mu) * rs * gg.x + bb.x);
    H[1] = f2h((v[j].y - mu) * rs * gg.y + bb.y);
    H[2] = f2h((v[j].z - mu) * rs * gg.z + bb.z);
    H[3] = f2h((v[j].w - mu) * rs * gg.w + bb.w);
    *(u16x4*)(orow + n) = H;
  }
}

// ---------------------------------------------------------------------------
// Tiled transpose+convert. in [R,C] -> out [C,R] (per z).
// MODE 0: f32 -> fp16;  MODE 2: fp16 -> fp16.
// ---------------------------------------------------------------------------
template <int MODE>
__global__ __launch_bounds__(256) void transpose_k(const void* __restrict__ in,
                                                   u16* __restrict__ out,
                                                   int R, int C, long zsIn,
                                                   long zsOut) {
  __shared__ float tile[32][33];
  const int z = blockIdx.z;
  const int c0 = blockIdx.x * 32, r0 = blockIdx.y * 32;
#pragma unroll
  for (int i = 0; i < 4; ++i) {
    const int lin = threadIdx.x + 256 * i;
    const int rr = lin >> 5, cc = lin & 31;
    float vv;
    if constexpr (MODE == 2)
      vv = h2f(((const u16*)in + (long)z * zsIn)[(long)(r0 + rr) * C + c0 + cc]);
    else
      vv = ((const float*)in)[(long)(r0 + rr) * C + c0 + cc];
    tile[rr][cc] = vv;
  }
  __syncthreads();
  u16* outz = out + (long)z * zsOut;
#pragma unroll
  for (int i = 0; i < 4; ++i) {
    const int lin = threadIdx.x + 256 * i;
    const int oc = lin >> 5, orr = lin & 31;
    outz[(long)(c0 + oc) * R + (r0 + orr)] = f2h(tile[orr][oc]);
  }
}

// ---------------------------------------------------------------------------
// Row softmax over 2048 cols, f32 in -> fp16 out IN-PLACE (P overwrites the
// first 4 KB of each 16 KB score row; all reads precede first barrier).
// ---------------------------------------------------------------------------
__global__ __launch_bounds__(256) void softmax_k(float* __restrict__ S) {
  const long row = blockIdx.x;
  float* sr = S + row * 2048;
  u16* pr = (u16*)sr;
  const int tid = threadIdx.x;
  const int lane = tid & 63, wv = tid >> 6;
  __shared__ float red[8];
  const float4 v0 = *(const float4*)(sr + tid * 4);
  const float4 v1 = *(const float4*)(sr + 1024 + tid * 4);
  float mx = fmaxf(fmaxf(fmaxf(v0.x, v0.y), fmaxf(v0.z, v0.w)),
                   fmaxf(fmaxf(v1.x, v1.y), fmaxf(v1.z, v1.w)));
#pragma unroll
  for (int o = 32; o; o >>= 1) mx = fmaxf(mx, __shfl_xor(mx, o));
  if (lane == 0) red[wv] = mx;
  __syncthreads();
  mx = fmaxf(fmaxf(red[0], red[1]), fmaxf(red[2], red[3]));
  float e[8];
  e[0] = __expf(v0.x - mx); e[1] = __expf(v0.y - mx);
  e[2] = __expf(v0.z - mx); e[3] = __expf(v0.w - mx);
  e[4] = __expf(v1.x - mx); e[5] = __expf(v1.y - mx);
  e[6] = __expf(v1.z - mx); e[7] = __expf(v1.w - mx);
  float sm = e[0] + e[1] + e[2] + e[3] + e[4] + e[5] + e[6] + e[7];
#pragma unroll
  for (int o = 32; o; o >>= 1) sm += __shfl_xor(sm, o);
  if (lane == 0) red[4 + wv] = sm;
  __syncthreads();
  sm = red[4] + red[5] + red[6] + red[7];
  const float inv = 1.f / sm;
  u16x4 a, b;
  a[0] = f2h(e[0] * inv); a[1] = f2h(e[1] * inv);
  a[2] = f2h(e[2] * inv); a[3] = f2h(e[3] * inv);
  b[0] = f2h(e[4] * inv); b[1] = f2h(e[5] * inv);
  b[2] = f2h(e[6] * inv); b[3] = f2h(e[7] * inv);
  *(u16x4*)(pr + tid * 4) = a;
  *(u16x4*)(pr + 1024 + tid * 4) = b;
}

// ---------------------------------------------------------------------------
extern "C" void kernel_launch(void* const* d_in, const int* in_sizes, int n_in,
                              void* d_out, int out_size, void* d_ws,
                              size_t ws_size, hipStream_t stream) {
  const float* x     = (const float*)d_in[0];  // [4,2048,1024]
  const float* w_qkv = (const float*)d_in[1];  // [1024,3072]
  const float* fc1_w = (const float*)d_in[2];  // [1024,4096]
  const float* fc1_b = (const float*)d_in[3];  // [4096]
  const float* fc2_w = (const float*)d_in[4];  // [4096,1024]
  const float* fc2_b = (const float*)d_in[5];  // [1024]
  const float* ln1_g = (const float*)d_in[6];
  const float* ln1_b = (const float*)d_in[7];
  const float* ln2_g = (const float*)d_in[8];
  const float* ln2_b = (const float*)d_in[9];
  float* out = (float*)d_out;

  // workspace (peak 160 MB, phase-aliased; all fp16 unless noted)
  char* ws = (char*)d_ws;
  const long MB = 1024L * 1024L;
  u16*   h    = (u16*)(ws + 0);          // 16MB [8192,1024]
  u16*   wqkT = (u16*)(ws + 16 * MB);    //  6MB [3072,1024]
  float* sc   = (float*)(ws + 0);        // 64MB f32 scores (h,wqkT dead)
  u16*   qk   = (u16*)(ws + 64 * MB);    // 32MB [8192,2048] (q|k)
  u16*   vbuf = (u16*)(ws + 96 * MB);    // 16MB [8192,1024]
  u16*   vT   = (u16*)(ws + 112 * MB);   // 16MB [4][1024][2048]
  u16*   w1T  = (u16*)(ws + 144 * MB);   //  8MB [4096,1024]
  u16*   w2T  = (u16*)(ws + 152 * MB);   //  8MB [1024,4096]
  float* r2   = (float*)(ws + 64 * MB);  // 32MB f32 (qk dead after GEMM2)
  u16*   h2   = (u16*)(ws + 96 * MB);    // 16MB (vbuf dead after vT)
  u16*   g    = (u16*)(ws + 0);          // 64MB [8192,4096] (sc/P dead)

  dim3 blk(256);

  // 1) LN1 -> h fp16
  ln_k<<<2048, blk, 0, stream>>>(x, ln1_g, ln1_b, h);
  // 2) w_qkv [1024,3072] -> wqkT [3072,1024] fp16
  transpose_k<0><<<dim3(3072 / 32, 1024 / 32, 1), blk, 0, stream>>>(
      w_qkv, wqkT, 1024, 3072, 0, 0);
  // 3) qkv-GEMM: h @ wqkv^T -> qk (n<2048) + vbuf.  grid 1536 = 6 rounds.
  gemm_nt<0, true><<<dim3(24, 64, 1), blk, 0, stream>>>(
      h, wqkT, 8192, 3072, 1024, 1024, 1024, 0, 0, 0, nullptr, qk, vbuf,
      nullptr, nullptr);
  // 4) v -> vT per batch
  transpose_k<2><<<dim3(1024 / 32, 2048 / 32, 4), blk, 0, stream>>>(
      vbuf, vT, 2048, 1024, 2048L * 1024, 1024L * 2048);
  // 5) GEMM2: scores[z] = q[z] @ k[z]^T (fp16, K=1024).  grid 256/z.
  gemm_nt<1, true><<<dim3(16, 16, 4), blk, 0, stream>>>(
      qk, qk + 1024, 2048, 2048, 1024, 2048, 2048, 2048L * 2048, 2048L * 2048,
      2048L * 2048, sc, nullptr, nullptr, nullptr, nullptr);
  // 6) softmax in-place: P (fp16, lda=4096 u16) overwrites score rows
  softmax_k<<<8192, blk, 0, stream>>>(sc);
  // 7) GEMM3: attn = P @ vT + resid -> r2.  grid 128/z.
  gemm_nt<2, true><<<dim3(8, 16, 4), blk, 0, stream>>>(
      (const u16*)sc, vT, 2048, 1024, 2048, 4096, 2048, 2048L * 4096,
      1024L * 2048, 2048L * 1024, r2, nullptr, nullptr, x, nullptr);
  // 8) LN2 -> h2 fp16
  ln_k<<<2048, blk, 0, stream>>>(r2, ln2_g, ln2_b, h2);
  // 9) fc1_w -> w1T, fc2_w -> w2T
  transpose_k<0><<<dim3(4096 / 32, 1024 / 32, 1), blk, 0, stream>>>(
      fc1_w, w1T, 1024, 4096, 0, 0);
  transpose_k<0><<<dim3(1024 / 32, 4096 / 32, 1), blk, 0, stream>>>(
      fc2_w, w2T, 4096, 1024, 0, 0);
  // 10) GEMM4: g = gelu(h2 @ fc1_w + b1) fp16.  grid 2048 = 8 rounds.
  gemm_nt<3, true><<<dim3(32, 64, 1), blk, 0, stream>>>(
      h2, w1T, 8192, 4096, 1024, 1024, 1024, 0, 0, 0, nullptr, g, nullptr,
      fc1_b, nullptr);
  // 11) GEMM5: out = g @ fc2_w + b2 + r2.  grid 512 = 2 rounds.
  gemm_nt<4, true><<<dim3(8, 64, 1), blk, 0, stream>>>(
      g, w2T, 8192, 1024, 4096, 4096, 4096, 0, 0, 0, out, nullptr, nullptr,
      fc2_b, r2);
}